// Round 6
// baseline (3396.558 us; speedup 1.0000x reference)
//
#include <hip/hip_runtime.h>

#define LL 8
#define BB 1024
#define DD 1024
#define FF 8192
#define PP 21

static constexpr long RECONS_N = (long)LL * BB * DD;   // 8388608
static constexpr long FEATS_N  = (long)LL * BB * FF;   // 67108864
static constexpr long RES_N    = RECONS_N;
static constexpr long ENCW_N   = (long)LL * FF * DD;   // 67108864
static constexpr long DECW_N   = (long)PP * DD * FF;   // 176160768

typedef __attribute__((ext_vector_type(8))) short short8;
typedef __attribute__((ext_vector_type(8))) unsigned short ushort8;
typedef __attribute__((ext_vector_type(4))) float f32x4;

__device__ __forceinline__ f32x4 mfma16(short8 a, short8 b, f32x4 c) {
    return __builtin_amdgcn_mfma_f32_16x16x32_bf16(a, b, c, 0, 0, 0);
}

// T1: bijective XCD-chunked swizzle (nwg % 8 == 0). HW round-robins bid across
// 8 XCDs; this gives XCD k the contiguous work chunk [k*cpx, (k+1)*cpx).
__device__ __forceinline__ int xcd_swizzle(int bid, int cpx) {
    return (bid & 7) * cpx + (bid >> 3);
}

// ---- fp32 -> (hi, lo) bf16 truncation split. x ~= hi + lo, err <= 2^-16 |x|.
__device__ __forceinline__ unsigned short hi16(float x) {
    return (unsigned short)(__float_as_uint(x) >> 16);
}
__device__ __forceinline__ unsigned short lo16(float x, unsigned short h) {
    const float r = x - __uint_as_float((unsigned int)h << 16);
    return (unsigned short)(__float_as_uint(r) >> 16);
}
__device__ __forceinline__ void split2(float x, unsigned short& h, unsigned short& l) {
    h = hi16(x);
    l = lo16(x, h);
}

// LDS tile: A/B each as hi and lo bf16 planes, K padded 32->40 (80 B row stride).
// 80 B stride => frag ds_read_b128 and staging ds_write_b128 both spread their
// 256 bank-requests uniformly (8/bank = the 8-cycle minimum) -> conflict-free.
struct alignas(16) Tile {
    unsigned short Ah[128][40];
    unsigned short Al[128][40];
    unsigned short Bh[128][40];
    unsigned short Bl[128][40];
};   // 40 KiB

// ---------- staging, split into load (global->regs) and write (regs->LDS) so
// ---------- the k+1 loads can be issued before compute(k)  [T14-lite, m249]

// planes path regs: 8 x ushort8 = 32 VGPR
struct StPlanes { ushort8 a0, a1, l0, l1, b0, b1, m0, m1; };

__device__ __forceinline__ void stage_load_planes(StPlanes& r,
        const unsigned short* __restrict__ Ah, const unsigned short* __restrict__ Al,
        const unsigned short* __restrict__ Bh, const unsigned short* __restrict__ Bl,
        int ldA, int ldB, int k0, int tid) {
    const int r0 = tid >> 2;
    const int c8 = (tid & 3) << 3;
    const size_t oa0 = (size_t)r0 * ldA + k0 + c8;
    const size_t oa1 = oa0 + (size_t)64 * ldA;
    const size_t ob0 = (size_t)r0 * ldB + k0 + c8;
    const size_t ob1 = ob0 + (size_t)64 * ldB;
    r.a0 = *reinterpret_cast<const ushort8*>(Ah + oa0);
    r.a1 = *reinterpret_cast<const ushort8*>(Ah + oa1);
    r.l0 = *reinterpret_cast<const ushort8*>(Al + oa0);
    r.l1 = *reinterpret_cast<const ushort8*>(Al + oa1);
    r.b0 = *reinterpret_cast<const ushort8*>(Bh + ob0);
    r.b1 = *reinterpret_cast<const ushort8*>(Bh + ob1);
    r.m0 = *reinterpret_cast<const ushort8*>(Bl + ob0);
    r.m1 = *reinterpret_cast<const ushort8*>(Bl + ob1);
}

__device__ __forceinline__ void stage_write_planes(Tile& t, const StPlanes& r, int tid) {
    const int r0 = tid >> 2;
    const int c8 = (tid & 3) << 3;
    *reinterpret_cast<ushort8*>(&t.Ah[r0     ][c8]) = r.a0;
    *reinterpret_cast<ushort8*>(&t.Ah[r0 + 64][c8]) = r.a1;
    *reinterpret_cast<ushort8*>(&t.Al[r0     ][c8]) = r.l0;
    *reinterpret_cast<ushort8*>(&t.Al[r0 + 64][c8]) = r.l1;
    *reinterpret_cast<ushort8*>(&t.Bh[r0     ][c8]) = r.b0;
    *reinterpret_cast<ushort8*>(&t.Bh[r0 + 64][c8]) = r.b1;
    *reinterpret_cast<ushort8*>(&t.Bl[r0     ][c8]) = r.m0;
    *reinterpret_cast<ushort8*>(&t.Bl[r0 + 64][c8]) = r.m1;
}

// fp32 fallback regs: 8 x float4 = 32 VGPR; split happens at write time.
struct StF32 { float4 a[4]; float4 b[4]; };

__device__ __forceinline__ void stage_load_f32(StF32& r, const float* __restrict__ Ag,
                                               const float* __restrict__ Bg,
                                               int ldA, int ldB, int k0, int tid) {
    const int rr = tid >> 3;
    const int c4 = (tid & 7) << 2;
    #pragma unroll
    for (int i = 0; i < 4; ++i) {
        const int row = rr + (i << 5);
        r.a[i] = *reinterpret_cast<const float4*>(Ag + (size_t)row * ldA + k0 + c4);
        r.b[i] = *reinterpret_cast<const float4*>(Bg + (size_t)row * ldB + k0 + c4);
    }
}

__device__ __forceinline__ void stage_write_f32(Tile& t, const StF32& r, int tid) {
    const int rr = tid >> 3;
    const int c4 = (tid & 7) << 2;
    #pragma unroll
    for (int i = 0; i < 4; ++i) {
        const int row = rr + (i << 5);
        ushort4 ah, al, bh, bl;   // HIP struct vectors: .x etc are real members
        split2(r.a[i].x, ah.x, al.x); split2(r.a[i].y, ah.y, al.y);
        split2(r.a[i].z, ah.z, al.z); split2(r.a[i].w, ah.w, al.w);
        split2(r.b[i].x, bh.x, bl.x); split2(r.b[i].y, bh.y, bl.y);
        split2(r.b[i].z, bh.z, bl.z); split2(r.b[i].w, bh.w, bl.w);
        *reinterpret_cast<ushort4*>(&t.Ah[row][c4]) = ah;
        *reinterpret_cast<ushort4*>(&t.Al[row][c4]) = al;
        *reinterpret_cast<ushort4*>(&t.Bh[row][c4]) = bh;
        *reinterpret_cast<ushort4*>(&t.Bl[row][c4]) = bl;
    }
}

// One K=32 step: each of 4 waves owns a 64x64 sub-tile (4x4 frags of 16x16).
// 3 MFMA passes per frag-pair: hi*hi + hi*lo + lo*hi (lo*lo ~ 2^-32 rel, dropped).
__device__ __forceinline__ void compute_step(const Tile& t, int tid, f32x4 acc[4][4]) {
    const int lane = tid & 63;
    const int wave = tid >> 6;
    const int wr = (wave >> 1) << 6;
    const int wc = (wave & 1) << 6;
    const int frow = lane & 15;
    const int koff = (lane >> 4) << 3;   // A/B frag: lane&15 = M/N, k = (lane>>4)*8 + j
    short8 ah[4], al[4], bh[4], bl[4];
    #pragma unroll
    for (int m = 0; m < 4; ++m) {
        ah[m] = *reinterpret_cast<const short8*>(&t.Ah[wr + m * 16 + frow][koff]);
        al[m] = *reinterpret_cast<const short8*>(&t.Al[wr + m * 16 + frow][koff]);
    }
    #pragma unroll
    for (int n = 0; n < 4; ++n) {
        bh[n] = *reinterpret_cast<const short8*>(&t.Bh[wc + n * 16 + frow][koff]);
        bl[n] = *reinterpret_cast<const short8*>(&t.Bl[wc + n * 16 + frow][koff]);
    }
    #pragma unroll
    for (int m = 0; m < 4; ++m)
        #pragma unroll
        for (int n = 0; n < 4; ++n) {
            acc[m][n] = mfma16(ah[m], bh[n], acc[m][n]);
            acc[m][n] = mfma16(ah[m], bl[n], acc[m][n]);
            acc[m][n] = mfma16(al[m], bh[n], acc[m][n]);
        }
}

// Block-wide reduce of up to two values, one atomic each. sm must be >=8 floats.
__device__ __forceinline__ void block_reduce2_atomic(float v0, float v1,
                                                     float* sm, int tid,
                                                     float* dst0, float* dst1) {
    #pragma unroll
    for (int off = 32; off > 0; off >>= 1) {
        v0 += __shfl_down(v0, off, 64);
        v1 += __shfl_down(v1, off, 64);
    }
    const int lane = tid & 63, w = tid >> 6;
    if (lane == 0) { sm[w] = v0; sm[4 + w] = v1; }
    __syncthreads();
    if (tid == 0) {
        atomicAdd(dst0, sm[0] + sm[1] + sm[2] + sm[3]);
        atomicAdd(dst1, sm[4] + sm[5] + sm[6] + sm[7]);
    }
}

// ---------------- split: fp32 array -> hi/lo bf16 planes (grid-stride, 8 floats/thread)
__global__ __launch_bounds__(256) void split_kernel(const float* __restrict__ in,
                                                    unsigned short* __restrict__ h,
                                                    unsigned short* __restrict__ l,
                                                    long n8) {
    const long stride = (long)gridDim.x * 256;
    for (long i = (long)blockIdx.x * 256 + threadIdx.x; i < n8; i += stride) {
        const long base = i * 8;
        const float4 a = *reinterpret_cast<const float4*>(in + base);
        const float4 b = *reinterpret_cast<const float4*>(in + base + 4);
        ushort8 hh, ll;
        hh[0] = hi16(a.x); ll[0] = lo16(a.x, hh[0]);
        hh[1] = hi16(a.y); ll[1] = lo16(a.y, hh[1]);
        hh[2] = hi16(a.z); ll[2] = lo16(a.z, hh[2]);
        hh[3] = hi16(a.w); ll[3] = lo16(a.w, hh[3]);
        hh[4] = hi16(b.x); ll[4] = lo16(b.x, hh[4]);
        hh[5] = hi16(b.y); ll[5] = lo16(b.y, hh[5]);
        hh[6] = hi16(b.z); ll[6] = lo16(b.z, hh[6]);
        hh[7] = hi16(b.w); ll[7] = lo16(b.w, hh[7]);
        *reinterpret_cast<ushort8*>(h + base) = hh;
        *reinterpret_cast<ushort8*>(l + base) = ll;
    }
}

// ---------------- encode: feats = relu(res . enc_w^T + enc_b)
// 1-D grid, 4096 blocks; XCD swizzle gives each XCD one full layer (chunk 512).
// Epilogue fuses sparsity stats: acc[1] += sum(v) (v>=0 so |v|=v),
// acc[2+l] += count(v>0)   [saves the 256 MB feats re-read].
template <int PLANES>
__global__ __launch_bounds__(256) void encode_kernel(
    const float* __restrict__ res, const float* __restrict__ encw,
    const unsigned short* __restrict__ res_h, const unsigned short* __restrict__ res_l,
    const unsigned short* __restrict__ encw_h, const unsigned short* __restrict__ encw_l,
    const float* __restrict__ encb,
    float* __restrict__ feats,
    unsigned short* __restrict__ feats_h, unsigned short* __restrict__ feats_l,
    float* __restrict__ gacc)
{
    __shared__ Tile t;
    __shared__ float sm[8];
    const int wg = xcd_swizzle(blockIdx.x, 512);   // nwg = 4096
    const int bcol = (wg & 63) << 7;               // F cols
    const int brow = ((wg >> 6) & 7) << 7;         // B rows
    const int l = wg >> 9;                         // layer
    const int tid = threadIdx.x;
    const size_t aoff = (size_t)l * BB * DD + (size_t)brow * DD;
    const size_t boff = (size_t)l * FF * DD + (size_t)bcol * DD;

    f32x4 acc[4][4] = {};
    if (PLANES) {
        StPlanes r;
        stage_load_planes(r, res_h + aoff, res_l + aoff, encw_h + boff, encw_l + boff,
                          DD, DD, 0, tid);
        for (int k0 = 0; k0 < DD; k0 += 32) {
            __syncthreads();                       // prior compute done with LDS
            stage_write_planes(t, r, tid);
            __syncthreads();
            if (k0 + 32 < DD)                      // prefetch k+1 while MFMAs run
                stage_load_planes(r, res_h + aoff, res_l + aoff, encw_h + boff,
                                  encw_l + boff, DD, DD, k0 + 32, tid);
            compute_step(t, tid, acc);
        }
    } else {
        StF32 r;
        stage_load_f32(r, res + aoff, encw + boff, DD, DD, 0, tid);
        for (int k0 = 0; k0 < DD; k0 += 32) {
            __syncthreads();
            stage_write_f32(t, r, tid);
            __syncthreads();
            if (k0 + 32 < DD)
                stage_load_f32(r, res + aoff, encw + boff, DD, DD, k0 + 32, tid);
            compute_step(t, tid, acc);
        }
    }

    // epilogue: C/D layout col=lane&15, row=(lane>>4)*4+reg (m89-verified)
    const int lane = tid & 63;
    const int wave = tid >> 6;
    const int wr = (wave >> 1) << 6;
    const int wc = (wave & 1) << 6;
    const int crow0 = (lane >> 4) << 2;
    const int ccol = lane & 15;
    float s_abs = 0.0f, s_cnt = 0.0f;
    #pragma unroll
    for (int n = 0; n < 4; ++n) {
        const int col = bcol + wc + n * 16 + ccol;
        const float bv = encb[(size_t)l * FF + col];
        #pragma unroll
        for (int m = 0; m < 4; ++m) {
            #pragma unroll
            for (int j = 0; j < 4; ++j) {
                const int row = brow + wr + m * 16 + crow0 + j;
                const float v = fmaxf(acc[m][n][j] + bv, 0.0f);
                const size_t idx = (size_t)l * BB * FF + (size_t)row * FF + col;
                feats[idx] = v;
                s_abs += v;
                s_cnt += (v > 0.0f) ? 1.0f : 0.0f;
                if (PLANES) {
                    const unsigned short h = hi16(v);
                    feats_h[idx] = h;
                    feats_l[idx] = lo16(v, h);
                }
            }
        }
    }
    block_reduce2_atomic(s_abs, s_cnt, sm, tid, &gacc[1], &gacc[2 + l]);
}

// ---------------- decode: recons[j] = sum_{i in src(j)} feats[i] . dec_w[p(i,j)]^T
// pairs (i,j), j-i<=2: pid(i,j) = (i<7 ? 3i : 20) + (j-i)   [verified vs enumeration]
// 1-D grid, 512 blocks; XCD swizzle gives each XCD one full target (chunk 64),
// so blocks sharing A-panels / B-panels are co-resident on one XCD's L2.
// Epilogue fuses recon loss: acc[0] += sum((recons - mtgt)^2).
template <int PLANES>
__global__ __launch_bounds__(256) void decode_kernel(
    const float* __restrict__ feats, const float* __restrict__ decw,
    const unsigned short* __restrict__ feats_h, const unsigned short* __restrict__ feats_l,
    const unsigned short* __restrict__ decw_h, const unsigned short* __restrict__ decw_l,
    const float* __restrict__ mtgt,
    float* __restrict__ recons,
    float* __restrict__ gacc)
{
    __shared__ Tile t;
    __shared__ float sm[8];
    const int wg = xcd_swizzle(blockIdx.x, 64);    // nwg = 512
    const int bcol = (wg & 7) << 7;                // D cols
    const int brow = ((wg >> 3) & 7) << 7;         // B rows
    const int tgt = wg >> 6;                       // target layer
    const int tid = threadIdx.x;

    f32x4 acc[4][4] = {};
    const int src_lo = tgt > 2 ? tgt - 2 : 0;
    for (int src = src_lo; src <= tgt; ++src) {
        const int pid = (src < 7 ? 3 * src : 20) + (tgt - src);
        const size_t aoff = (size_t)src * BB * FF + (size_t)brow * FF;
        const size_t boff = (size_t)pid * DD * FF + (size_t)bcol * FF;
        if (PLANES) {
            StPlanes r;
            stage_load_planes(r, feats_h + aoff, feats_l + aoff, decw_h + boff,
                              decw_l + boff, FF, FF, 0, tid);
            for (int k0 = 0; k0 < FF; k0 += 32) {
                __syncthreads();
                stage_write_planes(t, r, tid);
                __syncthreads();
                if (k0 + 32 < FF)
                    stage_load_planes(r, feats_h + aoff, feats_l + aoff, decw_h + boff,
                                      decw_l + boff, FF, FF, k0 + 32, tid);
                compute_step(t, tid, acc);
            }
        } else {
            StF32 r;
            stage_load_f32(r, feats + aoff, decw + boff, FF, FF, 0, tid);
            for (int k0 = 0; k0 < FF; k0 += 32) {
                __syncthreads();
                stage_write_f32(t, r, tid);
                __syncthreads();
                if (k0 + 32 < FF)
                    stage_load_f32(r, feats + aoff, decw + boff, FF, FF, k0 + 32, tid);
                compute_step(t, tid, acc);
            }
        }
    }

    const int lane = tid & 63;
    const int wave = tid >> 6;
    const int wr = (wave >> 1) << 6;
    const int wc = (wave & 1) << 6;
    const int crow0 = (lane >> 4) << 2;
    const int ccol = lane & 15;
    float s_sq = 0.0f;
    #pragma unroll
    for (int n = 0; n < 4; ++n) {
        const int col = bcol + wc + n * 16 + ccol;
        #pragma unroll
        for (int m = 0; m < 4; ++m) {
            #pragma unroll
            for (int j = 0; j < 4; ++j) {
                const int row = brow + wr + m * 16 + crow0 + j;
                const size_t idx = (size_t)tgt * BB * DD + (size_t)row * DD + col;
                const float v = acc[m][n][j];
                recons[idx] = v;
                const float d = v - mtgt[idx];
                s_sq += d * d;
            }
        }
    }
    block_reduce2_atomic(s_sq, 0.0f, sm, tid, &gacc[0], &gacc[15]);  // gacc[15] unused pad
}

__global__ void finalize_kernel(const float* __restrict__ acc, float* __restrict__ tail) {
    if (threadIdx.x == 0) {
        const float recon = acc[0] / (float)RECONS_N;
        const float sp = 1e-4f * acc[1] / (float)FEATS_N;
        tail[0] = recon + sp;   // loss
        tail[1] = recon;        // recon_loss
        tail[2] = sp;           // sparsity_loss
    }
    if (threadIdx.x < 8) tail[3 + threadIdx.x] = acc[2 + threadIdx.x] / (float)BB;
}

extern "C" void kernel_launch(void* const* d_in, const int* in_sizes, int n_in,
                              void* d_out, int out_size, void* d_ws, size_t ws_size,
                              hipStream_t stream) {
    const float* res  = (const float*)d_in[0];   // [L][B][D]
    const float* mtgt = (const float*)d_in[1];   // [L][B][D]
    const float* encw = (const float*)d_in[2];   // [L][F][D]
    const float* encb = (const float*)d_in[3];   // [L][F]
    const float* decw = (const float*)d_in[4];   // [P][D][F]

    float* out = (float*)d_out;
    float* recons = out;                          // [L][B][D]
    float* feats  = out + RECONS_N;               // [L][B][F]
    float* tail   = out + RECONS_N + FEATS_N;     // loss, recon, sparsity, l0[8]

    // ws layout: acc (256 B) | res_h | res_l | encw_h | encw_l | decw_h | decw_l | feats_h | feats_l
    char* w = (char*)d_ws;
    float* acc = (float*)w;
    size_t off = 256;
    unsigned short* res_h   = (unsigned short*)(w + off); off += (size_t)RES_N * 2;
    unsigned short* res_l   = (unsigned short*)(w + off); off += (size_t)RES_N * 2;
    unsigned short* encw_h  = (unsigned short*)(w + off); off += (size_t)ENCW_N * 2;
    unsigned short* encw_l  = (unsigned short*)(w + off); off += (size_t)ENCW_N * 2;
    unsigned short* decw_h  = (unsigned short*)(w + off); off += (size_t)DECW_N * 2;
    unsigned short* decw_l  = (unsigned short*)(w + off); off += (size_t)DECW_N * 2;
    unsigned short* feats_h = (unsigned short*)(w + off); off += (size_t)FEATS_N * 2;
    unsigned short* feats_l = (unsigned short*)(w + off); off += (size_t)FEATS_N * 2;
    const bool planes = ws_size >= off;

    hipMemsetAsync(acc, 0, 16 * sizeof(float), stream);

    if (planes) {
        split_kernel<<<2048, 256, 0, stream>>>(res,  res_h,  res_l,  RES_N / 8);
        split_kernel<<<2048, 256, 0, stream>>>(encw, encw_h, encw_l, ENCW_N / 8);
        split_kernel<<<2048, 256, 0, stream>>>(decw, decw_h, decw_l, DECW_N / 8);
        encode_kernel<1><<<4096, 256, 0, stream>>>(res, encw, res_h, res_l, encw_h, encw_l,
                                                   encb, feats, feats_h, feats_l, acc);
        decode_kernel<1><<<512, 256, 0, stream>>>(feats, decw, feats_h, feats_l,
                                                  decw_h, decw_l, mtgt, recons, acc);
    } else {
        encode_kernel<0><<<4096, 256, 0, stream>>>(res, encw, nullptr, nullptr, nullptr,
                                                   nullptr, encb, feats, nullptr, nullptr, acc);
        decode_kernel<0><<<512, 256, 0, stream>>>(feats, decw, nullptr, nullptr,
                                                  nullptr, nullptr, mtgt, recons, acc);
    }

    finalize_kernel<<<1, 64, 0, stream>>>(acc, tail);
}